// Round 20
// baseline (130.085 us; speedup 1.0000x reference)
//
#include <hip/hip_runtime.h>
#include <math.h>

#define B_DIM 128
#define N_DIM 512
#define D_DIM 512
#define H_DIM 256
#define K_SEL 8

typedef _Float16 half8 __attribute__((ext_vector_type(8)));
typedef float    f32x4 __attribute__((ext_vector_type(4)));

__device__ __forceinline__ void gload_lds16(const void* g, void* l) {
    __builtin_amdgcn_global_load_lds((const __attribute__((address_space(1))) void*)g,
                                     (__attribute__((address_space(3))) void*)l, 16, 0, 0);
}

// ---------------- prep W1 -> MFMA-frag-ordered fp16 h/l' tables (proven r15-r19) ------
// w1frag[(c4*16 + ks)*512 + lane*8 + j]: col = c4*16 + (lane&15), k = ks*32 + (lane>>4)*8 + j.
// Split: x = h + l'/2048 + eps, |eps| <= 2^-22|x|.
__global__ __launch_bounds__(512) void prep_w1_kernel(
    const float* __restrict__ W1,          // (512, 256) [k][col]
    _Float16* __restrict__ w1frag_h,
    _Float16* __restrict__ w1frag_l)
{
    const int b    = blockIdx.x;           // 0..255 = c4*16 + ks
    const int c4   = b >> 4;
    const int ks   = b & 15;
    const int lane = threadIdx.x >> 3;     // 0..63
    const int j    = threadIdx.x & 7;
    const int col  = c4 * 16 + (lane & 15);
    const int k    = ks * 32 + (lane >> 4) * 8 + j;
    float x = W1[(size_t)k * H_DIM + col];
    _Float16 h = (_Float16)x;
    float r = x - (float)h;
    size_t o = (size_t)b * 512 + lane * 8 + j;
    w1frag_h[o] = h;
    w1frag_l[o] = (_Float16)(r * 2048.0f);
}

// ---------------- prep X -> MFMA-B-frag-ordered fp16 h/l' tables in d_ws (r17-proven) --
// xfrag[(rb*16 + ks)*512 + lane*8 + j]: token = rb*16 + (lane&15), k = ks*32 + (lane>>4)*8 + j.
// Eliminates the 4x-redundant in-loop split8 (27% VALUBusy in r19).
__global__ __launch_bounds__(512) void prep_x_kernel(
    const float* __restrict__ X,           // (65536, 512)
    _Float16* __restrict__ xfrag_h,
    _Float16* __restrict__ xfrag_l)
{
    const int rb   = blockIdx.x;           // 0..4095 (16-token block)
    const int lane = threadIdx.x & 63;
    const int ks8  = threadIdx.x >> 6;     // 0..7
    const int row  = rb * 16 + (lane & 15);
    const int lg   = lane >> 4;
    #pragma unroll
    for (int kk = 0; kk < 2; ++kk) {
        int ks = ks8 + kk * 8;
        const float* xp = X + (size_t)row * D_DIM + ks * 32 + lg * 8;
        float4 a = *reinterpret_cast<const float4*>(xp);
        float4 b = *reinterpret_cast<const float4*>(xp + 4);
        float e[8] = {a.x, a.y, a.z, a.w, b.x, b.y, b.z, b.w};
        half8 hh, ll;
        #pragma unroll
        for (int j = 0; j < 8; ++j) {
            _Float16 h = (_Float16)e[j];
            float r = e[j] - (float)h;
            hh[j] = h;
            ll[j] = (_Float16)(r * 2048.0f);
        }
        size_t o = ((size_t)rb * 16 + ks) * 512 + lane * 8;
        *reinterpret_cast<half8*>(xfrag_h + o) = hh;
        *reinterpret_cast<half8*>(xfrag_l + o) = ll;
    }
}

// bid mapping: all 4 quarters of token-group g land on the SAME XCD (bid%8 == g&7)
// within 32 consecutive bids -> concurrent, L2-deduped X reads (per-XCD L2 is private).
__device__ __forceinline__ void decode_bid(int bid, int& q, int& g) {
    q = (bid >> 3) & 3;
    g = ((bid >> 5) << 3) | (bid & 7);
}

// ---------------- scorer: W LDS-resident + pre-split X, barrier-free loop -------------
// W 64-col slice fully in LDS (staged once, frag-ordered DMA); X read as ready-made
// fp16 h/l B-frags (contiguous 1 KB/wave). No in-loop split, no in-loop barrier.
// Wave = 32 tokens x 64 cols; per k-step: 4 X loads + 8 W ds_read_b128 + 24 MFMAs.
// D-layout (r14/r17/r19-verified): token = lane&15, hidden = m*16 + (lane>>4)*4 + r.
__global__ __launch_bounds__(512, 1) void fused_scorer_wx(
    const _Float16* __restrict__ xfrag_h,  // (33554432)
    const _Float16* __restrict__ xfrag_l,
    const _Float16* __restrict__ w1frag_h, // (131072)
    const _Float16* __restrict__ w1frag_l,
    const float* __restrict__ b1,          // (256)
    const float* __restrict__ W2,          // (256)
    float* __restrict__ lp)                // (4, 65536) partial logits
{
    __shared__ half8 Wh[4096], Wl[4096];   // [(m*16+ks)*64 + lane] -> 64 KB + 64 KB

    const int tid  = threadIdx.x;
    const int lane = tid & 63;
    const int wave = tid >> 6;             // 0..7
    const int lg   = lane >> 4;            // 0..3
    int q, g;
    decode_bid(blockIdx.x, q, g);
    const int tok0 = (g * 8 + wave) * 32;
    const int rb0  = tok0 >> 4;            // token-blocks rb0 (tg=0), rb0+1 (tg=1)

    // ---- stage the 64-col W slice once: 64 chunks of 1 KB per table ----
    #pragma unroll
    for (int c = wave; c < 64; c += 8) {   // c = m*16+ks ; global chunk = q*64 + c
        size_t so = ((size_t)(q * 64 + c)) * 512 + lane * 8;
        gload_lds16(w1frag_h + so, &Wh[c * 64 + lane]);
        gload_lds16(w1frag_l + so, &Wl[c * 64 + lane]);
    }

    f32x4 acc[4][2], acc2[4][2];           // [m][tg] — static indexing only
    #pragma unroll
    for (int m = 0; m < 4; ++m)
        #pragma unroll
        for (int tg = 0; tg < 2; ++tg) {
            acc[m][tg]  = (f32x4){0.f, 0.f, 0.f, 0.f};
            acc2[m][tg] = (f32x4){0.f, 0.f, 0.f, 0.f};
        }

    const _Float16* xh0 = xfrag_h + ((size_t)(rb0)     * 16) * 512 + lane * 8;
    const _Float16* xl0 = xfrag_l + ((size_t)(rb0)     * 16) * 512 + lane * 8;
    const _Float16* xh1 = xfrag_h + ((size_t)(rb0 + 1) * 16) * 512 + lane * 8;
    const _Float16* xl1 = xfrag_l + ((size_t)(rb0 + 1) * 16) * 512 + lane * 8;

    // 1-step-ahead prefetch in NAMED registers (rule #20: no runtime-indexed arrays)
    half8 cxh0 = *reinterpret_cast<const half8*>(xh0);
    half8 cxl0 = *reinterpret_cast<const half8*>(xl0);
    half8 cxh1 = *reinterpret_cast<const half8*>(xh1);
    half8 cxl1 = *reinterpret_cast<const half8*>(xl1);

    __syncthreads();                       // W slice ready; ONLY barrier in the kernel

    #pragma unroll
    for (int ks = 0; ks < 16; ++ks) {
        half8 bxh0 = cxh0, bxl0 = cxl0, bxh1 = cxh1, bxl1 = cxl1;
        if (ks < 15) {
            const int o = (ks + 1) * 512;
            cxh0 = *reinterpret_cast<const half8*>(xh0 + o);
            cxl0 = *reinterpret_cast<const half8*>(xl0 + o);
            cxh1 = *reinterpret_cast<const half8*>(xh1 + o);
            cxl1 = *reinterpret_cast<const half8*>(xl1 + o);
        }
        #pragma unroll
        for (int m = 0; m < 4; ++m) {
            const int c = (m * 16 + ks) * 64 + lane;
            half8 wh = Wh[c];
            half8 wl = Wl[c];
            acc[m][0]  = __builtin_amdgcn_mfma_f32_16x16x32_f16(wh, bxh0, acc[m][0],  0, 0, 0);
            acc2[m][0] = __builtin_amdgcn_mfma_f32_16x16x32_f16(wh, bxl0, acc2[m][0], 0, 0, 0);
            acc2[m][0] = __builtin_amdgcn_mfma_f32_16x16x32_f16(wl, bxh0, acc2[m][0], 0, 0, 0);
            acc[m][1]  = __builtin_amdgcn_mfma_f32_16x16x32_f16(wh, bxh1, acc[m][1],  0, 0, 0);
            acc2[m][1] = __builtin_amdgcn_mfma_f32_16x16x32_f16(wh, bxl1, acc2[m][1], 0, 0, 0);
            acc2[m][1] = __builtin_amdgcn_mfma_f32_16x16x32_f16(wl, bxh1, acc2[m][1], 0, 0, 0);
        }
    }

    // ---- epilogue: z = acc + acc2/2048 + b1 ; exact GELU ; dot W2 ; reduce over lg ----
    float part[2] = {0.f, 0.f};
    #pragma unroll
    for (int m = 0; m < 4; ++m) {
        const int col4 = q * 64 + m * 16 + lg * 4;
        float4 b1v = *reinterpret_cast<const float4*>(b1 + col4);
        float4 w2v = *reinterpret_cast<const float4*>(W2 + col4);
        float bb[4] = {b1v.x, b1v.y, b1v.z, b1v.w};
        float ww[4] = {w2v.x, w2v.y, w2v.z, w2v.w};
        #pragma unroll
        for (int tg = 0; tg < 2; ++tg)
            #pragma unroll
            for (int r = 0; r < 4; ++r) {
                float z = acc[m][tg][r] + acc2[m][tg][r] * (1.0f / 2048.0f) + bb[r];
                float gl = 0.5f * z * (1.0f + erff(z * 0.70710678118654752440f));
                part[tg] = fmaf(gl, ww[r], part[tg]);
            }
    }
    #pragma unroll
    for (int tg = 0; tg < 2; ++tg) {
        float v = part[tg];
        v += __shfl_xor(v, 16, 64);
        v += __shfl_xor(v, 32, 64);
        if (lane < 16)
            lp[(size_t)q * 65536 + tok0 + tg * 16 + lane] = v;
    }
}

// ---------------- FALLBACK scorer (r19 verbatim + new bid mapping; no d_ws needed) ----
__global__ __launch_bounds__(512, 1) void fused_scorer_wlds(
    const float* __restrict__ X,
    const _Float16* __restrict__ w1frag_h,
    const _Float16* __restrict__ w1frag_l,
    const float* __restrict__ b1,
    const float* __restrict__ W2,
    float* __restrict__ lp)
{
    __shared__ half8 Wh[4096], Wl[4096];

    const int tid  = threadIdx.x;
    const int lane = tid & 63;
    const int wave = tid >> 6;
    const int l15  = lane & 15;
    const int lg   = lane >> 4;
    int quarter, wgq;
    decode_bid(blockIdx.x, quarter, wgq);
    const int tok0 = (wgq * 8 + wave) * 32;

    #pragma unroll
    for (int c = wave; c < 64; c += 8) {
        size_t so = ((size_t)(quarter * 64 + c)) * 512 + lane * 8;
        gload_lds16(w1frag_h + so, &Wh[c * 64 + lane]);
        gload_lds16(w1frag_l + so, &Wl[c * 64 + lane]);
    }

    f32x4 acc[4][2], acc2[4][2];
    #pragma unroll
    for (int m = 0; m < 4; ++m)
        #pragma unroll
        for (int tg = 0; tg < 2; ++tg) {
            acc[m][tg]  = (f32x4){0.f, 0.f, 0.f, 0.f};
            acc2[m][tg] = (f32x4){0.f, 0.f, 0.f, 0.f};
        }

    const float* xp0 = X + (size_t)(tok0 + l15) * D_DIM + lg * 8;
    const float* xp1 = xp0 + (size_t)16 * D_DIM;

    auto split8 = [&](float4 a, float4 b, half8& hh, half8& ll) {
        float e[8] = {a.x, a.y, a.z, a.w, b.x, b.y, b.z, b.w};
        #pragma unroll
        for (int j = 0; j < 8; ++j) {
            _Float16 h = (_Float16)e[j];
            float r = e[j] - (float)h;
            hh[j] = h;
            ll[j] = (_Float16)(r * 2048.0f);
        }
    };

    float4 xvA[2][2], xvB[2][2];
    xvA[0][0] = *reinterpret_cast<const float4*>(xp0);
    xvA[0][1] = *reinterpret_cast<const float4*>(xp0 + 4);
    xvA[1][0] = *reinterpret_cast<const float4*>(xp1);
    xvA[1][1] = *reinterpret_cast<const float4*>(xp1 + 4);
    xvB[0][0] = *reinterpret_cast<const float4*>(xp0 + 32);
    xvB[0][1] = *reinterpret_cast<const float4*>(xp0 + 36);
    xvB[1][0] = *reinterpret_cast<const float4*>(xp1 + 32);
    xvB[1][1] = *reinterpret_cast<const float4*>(xp1 + 36);

    __syncthreads();

    #pragma unroll 2
    for (int ks2 = 0; ks2 < 16; ks2 += 2) {
        {
            half8 bxh[2], bxl[2];
            split8(xvA[0][0], xvA[0][1], bxh[0], bxl[0]);
            split8(xvA[1][0], xvA[1][1], bxh[1], bxl[1]);
            if (ks2 + 2 < 16) {
                const int ko = (ks2 + 2) * 32;
                xvA[0][0] = *reinterpret_cast<const float4*>(xp0 + ko);
                xvA[0][1] = *reinterpret_cast<const float4*>(xp0 + ko + 4);
                xvA[1][0] = *reinterpret_cast<const float4*>(xp1 + ko);
                xvA[1][1] = *reinterpret_cast<const float4*>(xp1 + ko + 4);
            }
            #pragma unroll
            for (int m = 0; m < 4; ++m) {
                const int c = (m * 16 + ks2) * 64 + lane;
                half8 wh = Wh[c];
                half8 wl = Wl[c];
                #pragma unroll
                for (int tg = 0; tg < 2; ++tg) {
                    acc[m][tg]  = __builtin_amdgcn_mfma_f32_16x16x32_f16(wh, bxh[tg], acc[m][tg],  0, 0, 0);
                    acc2[m][tg] = __builtin_amdgcn_mfma_f32_16x16x32_f16(wh, bxl[tg], acc2[m][tg], 0, 0, 0);
                    acc2[m][tg] = __builtin_amdgcn_mfma_f32_16x16x32_f16(wl, bxh[tg], acc2[m][tg], 0, 0, 0);
                }
            }
        }
        {
            half8 bxh[2], bxl[2];
            split8(xvB[0][0], xvB[0][1], bxh[0], bxl[0]);
            split8(xvB[1][0], xvB[1][1], bxh[1], bxl[1]);
            if (ks2 + 3 < 16) {
                const int ko = (ks2 + 3) * 32;
                xvB[0][0] = *reinterpret_cast<const float4*>(xp0 + ko);
                xvB[0][1] = *reinterpret_cast<const float4*>(xp0 + ko + 4);
                xvB[1][0] = *reinterpret_cast<const float4*>(xp1 + ko);
                xvB[1][1] = *reinterpret_cast<const float4*>(xp1 + ko + 4);
            }
            #pragma unroll
            for (int m = 0; m < 4; ++m) {
                const int c = (m * 16 + ks2 + 1) * 64 + lane;
                half8 wh = Wh[c];
                half8 wl = Wl[c];
                #pragma unroll
                for (int tg = 0; tg < 2; ++tg) {
                    acc[m][tg]  = __builtin_amdgcn_mfma_f32_16x16x32_f16(wh, bxh[tg], acc[m][tg],  0, 0, 0);
                    acc2[m][tg] = __builtin_amdgcn_mfma_f32_16x16x32_f16(wh, bxl[tg], acc2[m][tg], 0, 0, 0);
                    acc2[m][tg] = __builtin_amdgcn_mfma_f32_16x16x32_f16(wl, bxh[tg], acc2[m][tg], 0, 0, 0);
                }
            }
        }
    }

    float part[2] = {0.f, 0.f};
    #pragma unroll
    for (int m = 0; m < 4; ++m) {
        const int col4 = quarter * 64 + m * 16 + lg * 4;
        float4 b1v = *reinterpret_cast<const float4*>(b1 + col4);
        float4 w2v = *reinterpret_cast<const float4*>(W2 + col4);
        float bb[4] = {b1v.x, b1v.y, b1v.z, b1v.w};
        float ww[4] = {w2v.x, w2v.y, w2v.z, w2v.w};
        #pragma unroll
        for (int tg = 0; tg < 2; ++tg)
            #pragma unroll
            for (int r = 0; r < 4; ++r) {
                float z = acc[m][tg][r] + acc2[m][tg][r] * (1.0f / 2048.0f) + bb[r];
                float gl = 0.5f * z * (1.0f + erff(z * 0.70710678118654752440f));
                part[tg] = fmaf(gl, ww[r], part[tg]);
            }
    }
    #pragma unroll
    for (int tg = 0; tg < 2; ++tg) {
        float v = part[tg];
        v += __shfl_xor(v, 16, 64);
        v += __shfl_xor(v, 32, 64);
        if (lane < 16)
            lp[(size_t)quarter * 65536 + tok0 + tg * 16 + lane] = v;
    }
}

// ---------------- softmax + top-8 + mask/importance/indices (sums 4 lp slices) --------
__global__ __launch_bounds__(256) void softmax_topk_kernel(
    const float* __restrict__ lp,          // (4, 65536)
    const float* __restrict__ b2p,
    const float* __restrict__ base_logits,
    float* __restrict__ out_mask,
    float* __restrict__ out_importance,
    float* __restrict__ out_indices)
{
    const int b = blockIdx.x;
    const int tid = threadIdx.x;
    __shared__ float probs[N_DIM];
    __shared__ float redf[4];
    __shared__ int   redi[4];
    __shared__ int   sel_idx[K_SEL];

    const float b2v = b2p[0];
    int i0g = b * N_DIM + tid;
    int i1g = i0g + 256;
    float l0 = (lp[i0g] + lp[65536 + i0g]) + (lp[131072 + i0g] + lp[196608 + i0g]);
    float l1 = (lp[i1g] + lp[65536 + i1g]) + (lp[131072 + i1g] + lp[196608 + i1g]);
    l0 += b2v + base_logits[tid];
    l1 += b2v + base_logits[tid + 256];

    float m = fmaxf(l0, l1);
    #pragma unroll
    for (int s = 32; s >= 1; s >>= 1) m = fmaxf(m, __shfl_xor(m, s, 64));
    if ((tid & 63) == 0) redf[tid >> 6] = m;
    __syncthreads();
    float gm = fmaxf(fmaxf(redf[0], redf[1]), fmaxf(redf[2], redf[3]));
    __syncthreads();

    float e0 = expf(l0 - gm), e1 = expf(l1 - gm);
    float ssum = e0 + e1;
    #pragma unroll
    for (int s = 32; s >= 1; s >>= 1) ssum += __shfl_xor(ssum, s, 64);
    if ((tid & 63) == 0) redf[tid >> 6] = ssum;
    __syncthreads();
    float denom = redf[0] + redf[1] + redf[2] + redf[3];
    float p0 = e0 / denom, p1 = e1 / denom;
    probs[tid] = p0;
    probs[tid + 256] = p1;
    out_importance[b * N_DIM + tid] = p0;
    out_importance[b * N_DIM + tid + 256] = p1;
    __syncthreads();

    for (int it = 0; it < K_SEL; ++it) {
        float v0 = probs[tid]; int i0 = tid;
        float v1 = probs[tid + 256];
        if (v1 > v0) { v0 = v1; i0 = tid + 256; }
        #pragma unroll
        for (int s = 32; s >= 1; s >>= 1) {
            float ov = __shfl_xor(v0, s, 64);
            int   oi = __shfl_xor(i0, s, 64);
            if (ov > v0 || (ov == v0 && oi < i0)) { v0 = ov; i0 = oi; }
        }
        if ((tid & 63) == 0) { redf[tid >> 6] = v0; redi[tid >> 6] = i0; }
        __syncthreads();
        if (tid == 0) {
            float bv = redf[0]; int bi = redi[0];
            for (int w = 1; w < 4; ++w)
                if (redf[w] > bv || (redf[w] == bv && redi[w] < bi)) { bv = redf[w]; bi = redi[w]; }
            sel_idx[it] = bi;
            probs[bi] = -1.0f;
        }
        __syncthreads();
    }

    float mk0 = 0.f, mk1 = 0.f;
    #pragma unroll
    for (int i = 0; i < K_SEL; ++i) {
        if (sel_idx[i] == tid)       mk0 = 1.f;
        if (sel_idx[i] == tid + 256) mk1 = 1.f;
    }
    out_mask[b * N_DIM + tid] = mk0;
    out_mask[b * N_DIM + tid + 256] = mk1;

    if (tid < K_SEL) out_indices[b * K_SEL + tid] = (float)sel_idx[tid];
}

// ---------------- gather selected rows (overwrites d_out scratch last) ----------------
__global__ __launch_bounds__(256) void gather_kernel(
    const float* __restrict__ X,
    const float* __restrict__ out_indices,
    float* __restrict__ out_selected)
{
    const int b = blockIdx.x;
    const int tid = threadIdx.x;
    __shared__ int sel[K_SEL];
    if (tid < K_SEL) sel[tid] = (int)out_indices[b * K_SEL + tid];
    __syncthreads();
    #pragma unroll
    for (int i = 0; i < 4; ++i) {
        int f = tid + 256 * i;
        int ki = f >> 7;
        int c4 = f & 127;
        float4 v = reinterpret_cast<const float4*>(
            X + ((size_t)b * N_DIM + sel[ki]) * D_DIM)[c4];
        reinterpret_cast<float4*>(
            out_selected + ((size_t)b * K_SEL + ki) * D_DIM)[c4] = v;
    }
}

extern "C" void kernel_launch(void* const* d_in, const int* in_sizes, int n_in,
                              void* d_out, int out_size, void* d_ws, size_t ws_size,
                              hipStream_t stream) {
    const float* X           = (const float*)d_in[0];
    const float* W1          = (const float*)d_in[1];
    const float* b1          = (const float*)d_in[2];
    const float* W2          = (const float*)d_in[3];
    const float* b2          = (const float*)d_in[4];
    const float* base_logits = (const float*)d_in[5];

    float* out            = (float*)d_out;
    float* out_selected   = out;                                  // 128*8*512 = 524288
    float* out_mask       = out_selected + B_DIM * K_SEL * D_DIM; // 128*512
    float* out_importance = out_mask + B_DIM * N_DIM;             // 128*512
    float* out_indices    = out_importance + B_DIM * N_DIM;       // 128*8

    // d_out scratch (gather overwrites out_selected last):
    //   [0      , 262144) lp: 4 x 65536 f32
    //   [262144 , 327680) w1frag_h (131072 halfs)
    //   [327680 , 393216) w1frag_l (131072 halfs)
    float*    lp       = out_selected;
    _Float16* w1frag_h = (_Float16*)(out_selected + 262144);
    _Float16* w1frag_l = (_Float16*)(out_selected + 327680);

    hipLaunchKernelGGL(prep_w1_kernel, dim3(256), dim3(512), 0, stream,
                       W1, w1frag_h, w1frag_l);

    const size_t XFRAG_ELEMS = (size_t)65536 * 512;                // 33554432 halfs/table
    const size_t WS_NEEDED   = XFRAG_ELEMS * 2 * sizeof(_Float16); // 128 MiB

    if (ws_size >= WS_NEEDED) {
        _Float16* xfrag_h = (_Float16*)d_ws;
        _Float16* xfrag_l = xfrag_h + XFRAG_ELEMS;
        hipLaunchKernelGGL(prep_x_kernel, dim3(4096), dim3(512), 0, stream,
                           X, xfrag_h, xfrag_l);
        hipLaunchKernelGGL(fused_scorer_wx, dim3(1024), dim3(512), 0, stream,
                           xfrag_h, xfrag_l, w1frag_h, w1frag_l, b1, W2, lp);
    } else {
        hipLaunchKernelGGL(fused_scorer_wlds, dim3(1024), dim3(512), 0, stream,
                           X, w1frag_h, w1frag_l, b1, W2, lp);
    }

    hipLaunchKernelGGL(softmax_topk_kernel, dim3(B_DIM), dim3(256), 0, stream,
                       lp, b2, base_logits, out_mask, out_importance, out_indices);
    hipLaunchKernelGGL(gather_kernel, dim3(B_DIM), dim3(256), 0, stream,
                       X, out_indices, out_selected);
}